// Round 1
// baseline (521.573 us; speedup 1.0000x reference)
//
#include <hip/hip_runtime.h>
#include <math.h>

// Deblocking filter, fully fused vertical+horizontal pass.
// H=W=8192, BS=8, ALPHA=0.1, BETA=0.05 (fixed by reference setup).
//
// stage1 (vertical pass) at (r, j) depends only on frame[r, j-2..j+2] in the
// SAME row, so the horizontal pass (which needs stage1 at rows i-2..i+2, same
// col) can recompute stage1 on the fly -> single kernel, one read + one write
// of the frame. Memory-bound: 512 MiB total traffic, ~90us roofline @6 TB/s.

static constexpr int W = 8192;
static constexpr int H = 8192;
#define ALPHA 0.1f
#define BETA  0.05f

__device__ __forceinline__ bool dmask(float p1, float p0, float q0, float q1) {
    // exact float32 semantics, matches numpy (single sub, fabs, strict <)
    return (fabsf(p0 - q0) < ALPHA) && (fabsf(p1 - p0) < BETA) && (fabsf(q1 - q0) < BETA);
}

// returns filtered p0  (numpy order: ((2*p1 + p0) + q0) + 2, then /4 — exact)
__device__ __forceinline__ float filt_p(float p1, float p0, float q0, float q1) {
    float v = (((2.0f * p1 + p0) + q0) + 2.0f) * 0.25f;
    return dmask(p1, p0, q0, q1) ? v : p0;
}
// returns filtered q0
__device__ __forceinline__ float filt_q(float p1, float p0, float q0, float q1) {
    float v = (((2.0f * q1 + q0) + p0) + 2.0f) * 0.25f;
    return dmask(p1, p0, q0, q1) ? v : q0;
}

struct Vec8 { float v[8]; };

// stage1 (vertical pass) for the aligned 8-column group [j0, j0+7] of `row`.
// col j0   is a q-col (c = j0,   valid if j0 != 0)
// col j0+7 is a p-col (c = j0+8, valid if j0+8 != W)
__device__ __forceinline__ Vec8 stage1_row8(const float* __restrict__ row, int j0) {
    const float4 a = *reinterpret_cast<const float4*>(row + j0);
    const float4 b = *reinterpret_cast<const float4*>(row + j0 + 4);
    Vec8 r;
    r.v[0] = a.x; r.v[1] = a.y; r.v[2] = a.z; r.v[3] = a.w;
    r.v[4] = b.x; r.v[5] = b.y; r.v[6] = b.z; r.v[7] = b.w;
    if (j0 != 0) {
        // q-side update at j0: p1=row[j0-2], p0=row[j0-1], q0=a.x, q1=a.y
        const float2 pm = *reinterpret_cast<const float2*>(row + j0 - 2); // 8B-aligned
        r.v[0] = filt_q(pm.x, pm.y, a.x, a.y);
    }
    if (j0 + 8 != W) {
        // p-side update at j0+7: p1=b.z, p0=b.w, q0=row[j0+8], q1=row[j0+9]
        const float2 qn = *reinterpret_cast<const float2*>(row + j0 + 8);
        r.v[7] = filt_p(b.z, b.w, qn.x, qn.y);
    }
    return r;
}

__global__ __launch_bounds__(256)
void deblock_fused(const float* __restrict__ in, float* __restrict__ out) {
    const int j0 = (blockIdx.x * blockDim.x + threadIdx.x) * 8; // 8 cols/thread
    const int i  = blockIdx.y;                                  // one row/block
    const float* row = in + (size_t)i * W;
    const int m8 = i & 7;
    Vec8 r;
    if (m8 == 7 && i != H - 1) {
        // horizontal p-row: out[i] = filt_p(s1[i-1], s1[i], s1[i+1], s1[i+2])
        Vec8 s0 = stage1_row8(row - W, j0);
        Vec8 s1 = stage1_row8(row, j0);
        Vec8 s2 = stage1_row8(row + W, j0);
        Vec8 s3 = stage1_row8(row + 2 * (size_t)W, j0);
        #pragma unroll
        for (int k = 0; k < 8; ++k) r.v[k] = filt_p(s0.v[k], s1.v[k], s2.v[k], s3.v[k]);
    } else if (m8 == 0 && i != 0) {
        // horizontal q-row: out[i] = filt_q(s1[i-2], s1[i-1], s1[i], s1[i+1])
        Vec8 s0 = stage1_row8(row - 2 * (size_t)W, j0);
        Vec8 s1 = stage1_row8(row - W, j0);
        Vec8 s2 = stage1_row8(row, j0);
        Vec8 s3 = stage1_row8(row + W, j0);
        #pragma unroll
        for (int k = 0; k < 8; ++k) r.v[k] = filt_q(s0.v[k], s1.v[k], s2.v[k], s3.v[k]);
    } else {
        // pass-through row: just the vertical pass
        r = stage1_row8(row, j0);
    }
    float* orow = out + (size_t)i * W + j0;
    *reinterpret_cast<float4*>(orow)     = make_float4(r.v[0], r.v[1], r.v[2], r.v[3]);
    *reinterpret_cast<float4*>(orow + 4) = make_float4(r.v[4], r.v[5], r.v[6], r.v[7]);
}

extern "C" void kernel_launch(void* const* d_in, const int* in_sizes, int n_in,
                              void* d_out, int out_size, void* d_ws, size_t ws_size,
                              hipStream_t stream) {
    const float* frame = (const float*)d_in[0];
    float* out = (float*)d_out;
    dim3 block(256, 1, 1);
    dim3 grid(W / (256 * 8), H, 1); // 4 x 8192 blocks, exact cover, no bounds checks
    deblock_fused<<<grid, block, 0, stream>>>(frame, out);
}

// Round 2
// 466.825 us; speedup vs baseline: 1.1173x; 1.1173x over previous
//
#include <hip/hip_runtime.h>
#include <math.h>

// Deblocking filter, fused vertical+horizontal, 8x8-tile-per-thread version.
// H=W=8192, BS=8, ALPHA=0.1, BETA=0.05 (fixed by reference setup).
//
// R1 post-mortem: one-row-per-thread was latency-bound (2.2 TB/s, VALUBusy 6%,
// occupancy 32%) — too little MLP per thread. Here each thread owns rows
// 8k+1..8k+8 of an 8-col group. The two filtered rows in that window (8k+7 and
// 8k+8) share the SAME four stage1 rows (8k+6..8k+9), so the tile needs only
// 9 input row-segments for 8 output rows, with ~18 independent vector loads
// per thread to hide HBM latency.

static constexpr int W = 8192;
static constexpr int H = 8192;
#define ALPHA 0.1f
#define BETA  0.05f

__device__ __forceinline__ bool dmask(float p1, float p0, float q0, float q1) {
    // exact float32 semantics, matches numpy (single sub, fabs, strict <)
    return (fabsf(p0 - q0) < ALPHA) && (fabsf(p1 - p0) < BETA) && (fabsf(q1 - q0) < BETA);
}
// filtered p0 (numpy op order: ((2*p1 + p0) + q0) + 2, then /4 — exact)
__device__ __forceinline__ float filt_p(float p1, float p0, float q0, float q1) {
    float v = (((2.0f * p1 + p0) + q0) + 2.0f) * 0.25f;
    return dmask(p1, p0, q0, q1) ? v : p0;
}
__device__ __forceinline__ float filt_q(float p1, float p0, float q0, float q1) {
    float v = (((2.0f * q1 + q0) + p0) + 2.0f) * 0.25f;
    return dmask(p1, p0, q0, q1) ? v : q0;
}

struct Vec8 { float v[8]; };

// stage1 (vertical pass) for aligned cols [j0, j0+7] of `row`.
__device__ __forceinline__ Vec8 stage1_row8(const float* __restrict__ row, int j0) {
    const float4 a = *reinterpret_cast<const float4*>(row + j0);
    const float4 b = *reinterpret_cast<const float4*>(row + j0 + 4);
    Vec8 r;
    r.v[0] = a.x; r.v[1] = a.y; r.v[2] = a.z; r.v[3] = a.w;
    r.v[4] = b.x; r.v[5] = b.y; r.v[6] = b.z; r.v[7] = b.w;
    if (j0 != 0) {  // q-side update at col j0
        const float2 pm = *reinterpret_cast<const float2*>(row + j0 - 2); // 8B aligned
        r.v[0] = filt_q(pm.x, pm.y, a.x, a.y);
    }
    if (j0 + 8 != W) {  // p-side update at col j0+7
        const float2 qn = *reinterpret_cast<const float2*>(row + j0 + 8);
        r.v[7] = filt_p(b.z, b.w, qn.x, qn.y);
    }
    return r;
}

__device__ __forceinline__ void store8(float* __restrict__ p, const Vec8& s) {
    *reinterpret_cast<float4*>(p)     = make_float4(s.v[0], s.v[1], s.v[2], s.v[3]);
    *reinterpret_cast<float4*>(p + 4) = make_float4(s.v[4], s.v[5], s.v[6], s.v[7]);
}

__global__ __launch_bounds__(256)
void deblock_tiled(const float* __restrict__ in, float* __restrict__ out) {
    const int j0 = (blockIdx.x * blockDim.x + threadIdx.x) * 8; // 8 cols/thread
    const int k  = blockIdx.y;                                  // tile: rows 8k+1..8k+8
    const size_t base = (size_t)(8 * k) * W;

    // rows 8k+1..8k+6: pass-through (vertical filter only); keep s1 of row 8k+6
    Vec8 s6;
    #pragma unroll
    for (int r = 1; r <= 6; ++r) {
        Vec8 s = stage1_row8(in + base + (size_t)r * W, j0);
        if (r == 6) s6 = s;
        store8(out + base + (size_t)r * W + j0, s);
    }

    if (k != H / 8 - 1) {
        // boundary row i = 8k+8 (in 8..8184): out[i-1]=filt_p, out[i]=filt_q,
        // both from stage1 rows 8k+6..8k+9
        Vec8 s7 = stage1_row8(in + base + (size_t)7 * W, j0);
        Vec8 s8 = stage1_row8(in + base + (size_t)8 * W, j0);
        Vec8 s9 = stage1_row8(in + base + (size_t)9 * W, j0);
        Vec8 rp, rq;
        #pragma unroll
        for (int c = 0; c < 8; ++c) {
            rp.v[c] = filt_p(s6.v[c], s7.v[c], s8.v[c], s9.v[c]);
            rq.v[c] = filt_q(s6.v[c], s7.v[c], s8.v[c], s9.v[c]);
        }
        store8(out + base + (size_t)7 * W + j0, rp);
        store8(out + base + (size_t)8 * W + j0, rq);
    } else {
        // last tile: row 8191 (m8==7 but i==H-1) is pass-through; row 8192
        // doesn't exist — handle row 0 (pass-through, untouched by h-pass) here
        Vec8 s7 = stage1_row8(in + base + (size_t)7 * W, j0);
        store8(out + base + (size_t)7 * W + j0, s7);
        Vec8 s0 = stage1_row8(in, j0);
        store8(out + j0, s0);
    }
}

extern "C" void kernel_launch(void* const* d_in, const int* in_sizes, int n_in,
                              void* d_out, int out_size, void* d_ws, size_t ws_size,
                              hipStream_t stream) {
    const float* frame = (const float*)d_in[0];
    float* out = (float*)d_out;
    dim3 block(256, 1, 1);
    // x: 1024 col-groups / 256 threads = 4 blocks; y: 1024 row-tiles
    dim3 grid(W / 8 / 256, H / 8, 1);
    deblock_tiled<<<grid, block, 0, stream>>>(frame, out);
}